// Round 5
// baseline (95.995 us; speedup 1.0000x reference)
//
#include <hip/hip_runtime.h>

#define N_NODES 20000
#define D 128
#define K 16
#define STEPS 2
#define E_EDGES 8192

#define SCORE_BLOCKS 2500          // 8 nodes per 256-thread block
#define EDGE_BLOCKS 512            // 512 threads = 8 waves/block -> 4096 waves, 2 edges/wave

// ws layout:
//   emb_h  : ushort[N*D]   5.12 MB   bf16 shadow of embeddings
//   nscore : float[N]                emb[i] . w_n
//   sscore : float[N]                emb[i] . w_s
//   wsum   : float[2*D]              sum_f layer_w[l][f][d]

__device__ __forceinline__ unsigned short f2bf(float f) {
    unsigned u = __float_as_uint(f);
    u += 0x7FFFu + ((u >> 16) & 1u);       // round-to-nearest-even
    return (unsigned short)(u >> 16);
}
__device__ __forceinline__ float bf2f(unsigned short h) {
    return __uint_as_float(((unsigned)h) << 16);
}

// ---------------------------------------------------------------------------
// Pre-pass: blocks [0,SCORE_BLOCKS) compute nscore/sscore and the bf16 shadow
// (one coalesced stream over emb); last block computes wsum and zeroes out.
// ---------------------------------------------------------------------------
__global__ __launch_bounds__(256) void pre_kernel(
    const float* __restrict__ emb, const float* __restrict__ fc_w,
    const float* __restrict__ layer_w,
    unsigned short* __restrict__ emb_h, float* __restrict__ nscore,
    float* __restrict__ sscore, float* __restrict__ wsum,
    float* __restrict__ out)
{
    const int b = blockIdx.x;
    const int t = threadIdx.x;

    if (b < SCORE_BLOCKS) {
        const int wave = (b * 256 + t) >> 6;
        const int lane = t & 63;
        const int half = lane >> 5, sub = lane & 31;
        const int node = 2 * wave + half;              // exact: 20000 total

        const float4 e4  = *(const float4*)(emb + (size_t)node * D + sub * 4);
        const float4 wn4 = *(const float4*)(fc_w + sub * 4);
        const float4 ws4 = *(const float4*)(fc_w + D + sub * 4);
        float dn = e4.x * wn4.x + e4.y * wn4.y + e4.z * wn4.z + e4.w * wn4.w;
        float ds = e4.x * ws4.x + e4.y * ws4.y + e4.z * ws4.z + e4.w * ws4.w;
        #pragma unroll
        for (int off = 16; off > 0; off >>= 1) {
            dn += __shfl_xor(dn, off, 64);
            ds += __shfl_xor(ds, off, 64);
        }
        if (sub == 0) { nscore[node] = dn; sscore[node] = ds; }

        ushort4 h;
        h.x = f2bf(e4.x); h.y = f2bf(e4.y); h.z = f2bf(e4.z); h.w = f2bf(e4.w);
        *(ushort4*)(emb_h + (size_t)node * D + sub * 4) = h;
    } else {
        const int l = t >> 7, d = t & 127;
        const float* p = layer_w + (size_t)l * D * D + d;
        float s = 0.f;
        #pragma unroll
        for (int f = 0; f < D; f += 16) {
            float tmp[16];
            #pragma unroll
            for (int j = 0; j < 16; ++j) tmp[j] = p[(size_t)(f + j) * D];
            #pragma unroll
            for (int j = 0; j < 16; ++j) s += tmp[j];
        }
        wsum[t] = s;
        if (t == 0) out[0] = 0.f;
    }
}

// ---------------------------------------------------------------------------
// Fused edge kernel: 4096 waves, 2 edges each. All pointer-chase loads for
// both edges are hoisted before any branch so the two dependency chains
// overlap; only the gather-heavy aggregation is behind the wave-uniform
// label branch. Lanes 0-31 own src, 32-63 own dst (4 dims each).
// ---------------------------------------------------------------------------
__global__ __launch_bounds__(512) void edge_kernel(
    const int* __restrict__ edges, const int* __restrict__ labels,
    const int* __restrict__ neighbors, const float* __restrict__ emb,
    const unsigned short* __restrict__ emb_h,
    const float* __restrict__ nscore, const float* __restrict__ sscore,
    const float* __restrict__ fc_b, const float* __restrict__ wsum,
    const float* __restrict__ layer_b, float* __restrict__ out)
{
    __shared__ float part[8];
    const int t = threadIdx.x;
    const int lane = t & 63, wv = t >> 6;
    const int half = lane >> 5, sub = lane & 31;
    const int gw = blockIdx.x * 8 + wv;               // 4096 waves
    const float bias = fc_b[0];
    const int step = sub >> 4;

    const float4 w0 = *(const float4*)(wsum + sub * 4);
    const float4 w1 = *(const float4*)(wsum + D + sub * 4);
    const float4 b0 = *(const float4*)(layer_b + sub * 4);
    const float4 b1 = *(const float4*)(layer_b + D + sub * 4);

    // ---- hoisted loads for both edges (unconditional, overlap both chains) ----
    int lab[2], node[2], idx[2];
    float ns[2], ssc[2];
    float4 x[2];
    #pragma unroll
    for (int i = 0; i < 2; ++i) {
        const int e = 2 * gw + i;
        lab[i]  = labels[e];
        node[i] = edges[2 * e + half];
    }
    #pragma unroll
    for (int i = 0; i < 2; ++i) {
        x[i]   = *(const float4*)(emb + (size_t)node[i] * D + sub * 4);
        idx[i] = neighbors[((size_t)step * N_NODES + node[i]) * K + (sub & 15)];
        ssc[i] = sscore[node[i]];
    }
    #pragma unroll
    for (int i = 0; i < 2; ++i) ns[i] = nscore[idx[i]];

    float local = 0.f;
    #pragma unroll
    for (int i = 0; i < 2; ++i) {
        float4 xx = x[i];
        if (lab[i] == 1) {
            // ---- inline attention: scores are precomputed dots ----
            const float raw = ns[i] + ssc[i] + bias;
            float sc = (raw >= 0.f) ? raw : 0.2f * raw;

            float m = sc;
            #pragma unroll
            for (int off = 8; off > 0; off >>= 1) m = fmaxf(m, __shfl_xor(m, off, 64));
            const float ex = __expf(sc - m);
            float den = ex;
            #pragma unroll
            for (int off = 8; off > 0; off >>= 1) den += __shfl_xor(den, off, 64);
            const float a = ex / den;

            xx.x *= (float)(STEPS * K); xx.y *= (float)(STEPS * K);
            xx.z *= (float)(STEPS * K); xx.w *= (float)(STEPS * K);
            const int base_lane = half << 5;
            #pragma unroll 8
            for (int k2 = 0; k2 < 32; ++k2) {
                const int   sl   = base_lane + k2;
                const int   idxk = __shfl(idx[i], sl, 64);
                const float ak   = __shfl(a, sl, 64);
                const ushort4 vh = *(const ushort4*)(emb_h + (size_t)idxk * D + sub * 4);
                xx.x += ak * bf2f(vh.x);
                xx.y += ak * bf2f(vh.y);
                xx.z += ak * bf2f(vh.z);
                xx.w += ak * bf2f(vh.w);
            }
        }

        // ---- 2-layer elementwise transform, sum over layers ----
        float4 ss;
        ss.x = fmaxf(xx.x * w0.x + b0.x, 0.f) + fmaxf(xx.x * w1.x + b1.x, 0.f);
        ss.y = fmaxf(xx.y * w0.y + b0.y, 0.f) + fmaxf(xx.y * w1.y + b1.y, 0.f);
        ss.z = fmaxf(xx.z * w0.z + b0.z, 0.f) + fmaxf(xx.z * w1.z + b1.z, 0.f);
        ss.w = fmaxf(xx.w * w0.w + b0.w, 0.f) + fmaxf(xx.w * w1.w + b1.w, 0.f);

        // ---- exchange src<->dst halves, squared diff, 32-lane reduce ----
        const float ox = __shfl_xor(ss.x, 32, 64);
        const float oy = __shfl_xor(ss.y, 32, 64);
        const float oz = __shfl_xor(ss.z, 32, 64);
        const float ow = __shfl_xor(ss.w, 32, 64);
        const float dx = ss.x - ox, dy = ss.y - oy, dz = ss.z - oz, dw = ss.w - ow;
        float v = dx * dx + dy * dy + dz * dz + dw * dw;
        #pragma unroll
        for (int off = 16; off > 0; off >>= 1) v += __shfl_xor(v, off, 64);

        const float pred = __expf(-(v * (1.0f / (float)D)));
        const float l = (float)lab[i] - pred;
        local += 0.5f * l * l;                         // identical on all lanes
    }

    if (lane == 0) part[wv] = local;
    __syncthreads();
    if (t == 0) {
        float s = 0.f;
        #pragma unroll
        for (int i = 0; i < 8; ++i) s += part[i];
        atomicAdd(out, s);
    }
}

extern "C" void kernel_launch(void* const* d_in, const int* in_sizes, int n_in,
                              void* d_out, int out_size, void* d_ws, size_t ws_size,
                              hipStream_t stream) {
    const int*   edges     = (const int*)  d_in[0];
    const int*   labels    = (const int*)  d_in[1];
    const int*   neighbors = (const int*)  d_in[2];
    const float* emb       = (const float*)d_in[3];
    const float* fc_w      = (const float*)d_in[4];
    const float* fc_b      = (const float*)d_in[5];
    const float* layer_w   = (const float*)d_in[6];
    const float* layer_b   = (const float*)d_in[7];
    float* out = (float*)d_out;

    unsigned short* emb_h = (unsigned short*)d_ws;
    float* nscore = (float*)((char*)d_ws + (size_t)N_NODES * D * 2);
    float* sscore = nscore + N_NODES;
    float* wsum   = sscore + N_NODES;

    pre_kernel<<<SCORE_BLOCKS + 1, 256, 0, stream>>>(
        emb, fc_w, layer_w, emb_h, nscore, sscore, wsum, out);

    edge_kernel<<<EDGE_BLOCKS, 512, 0, stream>>>(
        edges, labels, neighbors, emb, emb_h, nscore, sscore,
        fc_b, wsum, layer_b, out);
}